// Round 1
// baseline (690.982 us; speedup 1.0000x reference)
//
#include <hip/hip_runtime.h>

// ---------- types / helpers ----------
typedef unsigned short u16;
typedef unsigned int   u32;
typedef __attribute__((ext_vector_type(4))) float  f32x4;
typedef __attribute__((ext_vector_type(8))) __bf16 bf16x8;
typedef __attribute__((ext_vector_type(8))) u16    u16x8;
typedef __attribute__((address_space(1))) void as1_void;
typedef __attribute__((address_space(3))) void as3_void;

__device__ __forceinline__ void async16(const void* g, void* l) {
  // global -> LDS direct copy, 16 B per lane; LDS dest = wave-uniform base + lane*16
  __builtin_amdgcn_global_load_lds((const as1_void*)g, (as3_void*)l, 16, 0, 0);
}

__device__ __forceinline__ u16 f2bf(float f) {
  u32 u = __builtin_bit_cast(u32, f);
  return (u16)((u + 0x7fffu + ((u >> 16) & 1u)) >> 16);  // RNE
}

// ---------- fp32 -> bf16 straight convert (hidden) ----------
__global__ __launch_bounds__(256) void cvt_bf16_kernel(const float* __restrict__ in,
                                                       u16* __restrict__ out, int n8) {
  int i = blockIdx.x * 256 + threadIdx.x;
  if (i >= n8) return;
  const float4* p = reinterpret_cast<const float4*>(in) + (size_t)i * 2;
  float4 a = p[0], b = p[1];
  u16x8 o;
  o[0] = f2bf(a.x); o[1] = f2bf(a.y); o[2] = f2bf(a.z); o[3] = f2bf(a.w);
  o[4] = f2bf(b.x); o[5] = f2bf(b.y); o[6] = f2bf(b.z); o[7] = f2bf(b.w);
  reinterpret_cast<u16x8*>(out)[i] = o;
}

// ---------- fp32 (K,N) -> bf16 (Npad,K) transpose-convert, zero-pad rows n>=N ----------
__global__ __launch_bounds__(256) void tconv_kernel(const float* __restrict__ in,
                                                    u16* __restrict__ out, int K, int N) {
  __shared__ float tile[32][33];  // +1 pad: conflict-free transposed read
  int tx = threadIdx.x & 31, ty = threadIdx.x >> 5;
  int n0 = blockIdx.x * 32, k0 = blockIdx.y * 32;
#pragma unroll
  for (int i = 0; i < 4; i++) {
    int k = k0 + ty + i * 8;
    int n = n0 + tx;
    tile[ty + i * 8][tx] = (n < N) ? in[(size_t)k * N + n] : 0.0f;
  }
  __syncthreads();
#pragma unroll
  for (int i = 0; i < 4; i++) {
    int nn = n0 + ty + i * 8;
    out[(size_t)nn * K + k0 + tx] = f2bf(tile[tx][ty + i * 8]);
  }
}

// ---------- 128x128-tile bf16 MFMA GEMM, B^T input (m97 structure) ----------
// A: (M x K) bf16 row-major. Bt: (Npad x K) bf16 row-major. K multiple of 32.
// STORE_BF16=false: C fp32, C[row*ldc + colOff + col] (col < Nreal only), optional
//                   row mask from target in [maskLo, maskHi).
// STORE_BF16=true : C bf16 row-major ld=ldc, no offset/mask.
template <bool STORE_BF16>
__global__ __launch_bounds__(256, 2)
void gemm_bt(const u16* __restrict__ A, const u16* __restrict__ Bt,
             void* __restrict__ Cout, int K, int ldc, int colOff, int Nreal,
             const int* __restrict__ target, int maskLo, int maskHi) {
  __shared__ u16 As[128 * 32];
  __shared__ u16 Bs[128 * 32];
  const int tid  = threadIdx.x;
  const int wid  = tid >> 6;
  const int lane = tid & 63;
  const int quad = lane >> 4;
  const int l16  = lane & 15;
  const int wm = (wid >> 1) * 64;
  const int wn = (wid & 1) * 64;
  const int bm = blockIdx.y * 128;
  const int bn = blockIdx.x * 128;

  f32x4 acc[4][4] = {};

  // staging map: lane -> (row, 8-elem chunk); wave w stages 1 KB at base w*1KB (+4KB for it=1)
  const int srow = wid * 16 + (lane >> 2);
  const int scol = (lane & 3) * 8;

  for (int k0 = 0; k0 < K; k0 += 32) {
    const u16* ga = A  + (size_t)(bm + srow) * K + k0 + scol;
    const u16* gb = Bt + (size_t)(bn + srow) * K + k0 + scol;
    async16(ga,                   As + wid * 512);
    async16(ga + (size_t)64 * K,  As + wid * 512 + 2048);
    async16(gb,                   Bs + wid * 512);
    async16(gb + (size_t)64 * K,  Bs + wid * 512 + 2048);
    __syncthreads();

    bf16x8 af[4], bfr[4];
#pragma unroll
    for (int i = 0; i < 4; i++) {
      af[i]  = *reinterpret_cast<const bf16x8*>(As + (wm + i * 16 + l16) * 32 + quad * 8);
      bfr[i] = *reinterpret_cast<const bf16x8*>(Bs + (wn + i * 16 + l16) * 32 + quad * 8);
    }
#pragma unroll
    for (int mi = 0; mi < 4; mi++)
#pragma unroll
      for (int ni = 0; ni < 4; ni++)
        acc[mi][ni] = __builtin_amdgcn_mfma_f32_16x16x32_bf16(af[mi], bfr[ni], acc[mi][ni], 0, 0, 0);
    __syncthreads();
  }

  // epilogue: C/D layout col = lane&15, row = quad*4 + reg  [m89/m91 verified]
#pragma unroll
  for (int mi = 0; mi < 4; mi++) {
    const int rbase = bm + wm + mi * 16 + quad * 4;
    float msk[4];
#pragma unroll
    for (int r = 0; r < 4; r++) {
      if (!STORE_BF16 && maskLo >= 0) {
        int t = target[rbase + r];
        msk[r] = (t >= maskLo && t < maskHi) ? 1.0f : 0.0f;
      } else {
        msk[r] = 1.0f;
      }
    }
#pragma unroll
    for (int ni = 0; ni < 4; ni++) {
      const int col = bn + wn + ni * 16 + l16;
      if (STORE_BF16) {
        u16* C = (u16*)Cout;
#pragma unroll
        for (int r = 0; r < 4; r++)
          C[(size_t)(rbase + r) * ldc + col] = f2bf(acc[mi][ni][r]);
      } else if (col < Nreal) {
        float* C = (float*)Cout;
#pragma unroll
        for (int r = 0; r < 4; r++)
          C[(size_t)(rbase + r) * ldc + colOff + col] = acc[mi][ni][r] * msk[r];
      }
    }
  }
}

// ---------- launch ----------
extern "C" void kernel_launch(void* const* d_in, const int* in_sizes, int n_in,
                              void* d_out, int out_size, void* d_ws, size_t ws_size,
                              hipStream_t stream) {
  const float* hidden = (const float*)d_in[0];  // (2048,1024)
  const int*   target = (const int*)d_in[1];    // (2048,)
  const float* head_w = (const float*)d_in[2];  // (1024,2002)
  const float* down0  = (const float*)d_in[3];  // (1024,1024)
  const float* dec0   = (const float*)d_in[4];  // (1024,8000)
  const float* down1  = (const float*)d_in[5];  // (1024,256)
  const float* dec1   = (const float*)d_in[6];  // (256,40000)
  float* out = (float*)d_out;                   // (2048,50002)

  // workspace layout (bf16), all offsets 16B-aligned
  char* ws = (char*)d_ws;
  const size_t NEED = 53280768;
  if (ws_size < NEED) return;  // visible failure instead of corruption
  u16* hA      = (u16*)(ws);                 // 2048x1024
  u16* head_wT = (u16*)(ws + 4194304);       // 2048x1024 (padded from 2002)
  u16* down0T  = (u16*)(ws + 8388608);       // 1024x1024
  u16* dec0T   = (u16*)(ws + 10485760);      // 8064x1024 (padded from 8000)
  u16* down1T  = (u16*)(ws + 27000832);      // 256x1024
  u16* dec1T   = (u16*)(ws + 27525120);      // 40064x256 (padded from 40000)
  u16* X0      = (u16*)(ws + 48037888);      // 2048x1024
  u16* X1      = (u16*)(ws + 52232192);      // 2048x256

  // 1) convert / transpose-convert all operands to bf16
  cvt_bf16_kernel<<<1024, 256, 0, stream>>>(hidden, hA, 262144);
  tconv_kernel<<<dim3(64, 32),  256, 0, stream>>>(head_w, head_wT, 1024, 2002);
  tconv_kernel<<<dim3(32, 32),  256, 0, stream>>>(down0,  down0T,  1024, 1024);
  tconv_kernel<<<dim3(252, 32), 256, 0, stream>>>(dec0,   dec0T,   1024, 8000);
  tconv_kernel<<<dim3(8, 32),   256, 0, stream>>>(down1,  down1T,  1024, 256);
  tconv_kernel<<<dim3(1252, 8), 256, 0, stream>>>(dec1,   dec1T,   256,  40000);

  const int LDC = 50002;
  // 2) head: (2048x1024)@(1024x2002) -> out[:, 0:2002]
  gemm_bt<false><<<dim3(16, 16), 256, 0, stream>>>(hA, head_wT, out, 1024, LDC, 0, 2002,
                                                   nullptr, -1, 0);
  // 3) X0 = hidden @ down0  (2048x1024 bf16)
  gemm_bt<true><<<dim3(8, 16), 256, 0, stream>>>(hA, down0T, X0, 1024, 1024, 0, 1024,
                                                 nullptr, -1, 0);
  // 4) tail0: X0 @ dec0 * m0 -> out[:, 2002:10002]
  gemm_bt<false><<<dim3(63, 16), 256, 0, stream>>>(X0, dec0T, out, 1024, LDC, 2002, 8000,
                                                   target, 2000, 10000);
  // 5) X1 = hidden @ down1  (2048x256 bf16)
  gemm_bt<true><<<dim3(2, 16), 256, 0, stream>>>(hA, down1T, X1, 1024, 256, 0, 256,
                                                 nullptr, -1, 0);
  // 6) tail1: X1 @ dec1 * m1 -> out[:, 10002:50002]
  gemm_bt<false><<<dim3(313, 16), 256, 0, stream>>>(X1, dec1T, out, 256, LDC, 10002, 40000,
                                                    target, 10000, 50000);
}